// Round 6
// baseline (301.659 us; speedup 1.0000x reference)
//
#include <hip/hip_runtime.h>
#include <hip/hip_bf16.h>

typedef unsigned short ushort_t;
typedef __attribute__((ext_vector_type(4))) float v4f;
typedef __attribute__((ext_vector_type(8))) short v8s;

#define FDIM 128
#define KCLUST 16
#define CSTRIDE 264   // combined-row stride in bf16 elems (264*2B = 528B)
#define QSTRIDE 24    // q row stride in shorts (48B)

__device__ __forceinline__ ushort_t f2bf(float x) {
    unsigned int u = __float_as_uint(x);
    unsigned int r = (u + 0x7fffu + ((u >> 16) & 1u)) >> 16;
    return (ushort_t)r;
}
__device__ __forceinline__ float bf2f(ushort_t h) {
    return __uint_as_float((unsigned int)h << 16);
}

union V8U { v8s v; ushort_t u[8]; };

// ---------------------------------------------------------------------------
// Kernel 1: cast weight (E x 256 f32) -> bf16, padded to Np rows (zeros).
// ---------------------------------------------------------------------------
__global__ void pack_weight(const float* __restrict__ W, ushort_t* __restrict__ Wb,
                            long total, long valid) {
    long i = ((long)blockIdx.x * blockDim.x + threadIdx.x) * 4;
    if (i >= total) return;
    float4 v;
    if (i < valid) v = *(const float4*)(W + i);
    else           v = make_float4(0.f, 0.f, 0.f, 0.f);
    ushort_t* dst = Wb + i;
    dst[0] = f2bf(v.x); dst[1] = f2bf(v.y); dst[2] = f2bf(v.z); dst[3] = f2bf(v.w);
}

// ---------------------------------------------------------------------------
// Kernel 2 (fused), v7: v6 structure at QUARTER block size.
//   8 rows / 256 threads / 4 waves / ~18 KB LDS -> ~6 blocks resident per CU
//   (v6: 512thr/36KB -> ~1.4 blocks; block-latency ~45K cycles with nothing
//   to overlap its barrier + wave0-serial + gather stalls). Cross-block
//   overlap is the lever; per-row math identical to v6.
//   MFMA tiles run half-empty (rows 8..15 mirror rows 0..7 via &7 reads;
//   stores guarded to quads 0,1) -- 2x per-row MFMA on a 4%-utilized pipe.
//   Each wave now owns TWO 16-col m-tiles (4 waves x 2 x 16 = 128 feats).
// ---------------------------------------------------------------------------
__global__ __launch_bounds__(256, 6) void fused_agg(
    const int* __restrict__ nodes, const int* __restrict__ neigh_idx,
    const float* __restrict__ self_table, const float* __restrict__ neigh_table,
    const float* __restrict__ center, const float* __restrict__ cluster_mask,
    const float* __restrict__ alpha, const ushort_t* __restrict__ Wb,
    float* __restrict__ out, int B, int S, int E) {

    __shared__ __align__(16) ushort_t comb[8 * CSTRIDE];      // 4224 B
    __shared__ __align__(16) ushort_t nbf[2][8 * 128];        // 4096 B (swizzled bf16 N)
    __shared__ __align__(16) float    nf32[2][8 * 132];       // 8448 B (f32 N, pad 132)
    __shared__ __align__(16) float    attL[2][8];
    __shared__ __align__(16) float    n2L[2][8];
    __shared__ __align__(16) ushort_t qhi[8 * QSTRIDE];       // 384 B
    __shared__ __align__(16) ushort_t qlo[8 * QSTRIDE];       // 384 B
    __shared__ __align__(16) float    invL[8];

    const int t    = threadIdx.x;
    const int lane = t & 63, wave = t >> 6;   // 4 waves
    const int row  = t >> 5;                  // 0..7 (2 rows per wave)
    const int fq   = t & 31;                  // feat-quad within row
    const int f0   = fq << 2;                 // first of this thread's 4 feats
    const int l16  = lane & 15, quad = lane >> 4;

    const int b0 = blockIdx.x * 8;
    int b = b0 + row; if (b >= B) b = B - 1;  // clamp loads; stores guarded

    const float4 aS = *(const float4*)(alpha + f0);
    const float4 aN = *(const float4*)(alpha + FDIM + f0);

    // ---- self features: stage to comb (bf16) + logit_self butterfly ----
    float ls;
    {
        size_t node = (size_t)nodes[b];
        float4 sf = *(const float4*)(self_table + node * FDIM + f0);
        ushort_t h0 = f2bf(sf.x), h1 = f2bf(sf.y), h2 = f2bf(sf.z), h3 = f2bf(sf.w);
        uint2 pk;
        pk.x = (unsigned)h0 | ((unsigned)h1 << 16);
        pk.y = (unsigned)h2 | ((unsigned)h3 << 16);
        *(uint2*)(comb + row * CSTRIDE + f0) = pk;
        ls = sf.x * aS.x + sf.y * aS.y + sf.z * aS.z + sf.w * aS.w;
        #pragma unroll
        for (int off = 1; off <= 16; off <<= 1) ls += __shfl_xor(ls, off, 64);
    }

    // ---- wave 0: center B-fragments (bf16) + c2 (exact f32) ----
    v8s cbf[4]; float c2v = 0.f;
    if (wave == 0) {
        const float* crow = center + l16 * FDIM;
        #pragma unroll
        for (int kk = 0; kk < 4; kk++) {
            const float* p = crow + kk * 32 + quad * 8;
            float4 x = *(const float4*)p;
            float4 y = *(const float4*)(p + 4);
            V8U pk;
            pk.u[0] = f2bf(x.x); pk.u[1] = f2bf(x.y); pk.u[2] = f2bf(x.z); pk.u[3] = f2bf(x.w);
            pk.u[4] = f2bf(y.x); pk.u[5] = f2bf(y.y); pk.u[6] = f2bf(y.z); pk.u[7] = f2bf(y.w);
            cbf[kk] = pk.v;
            c2v += x.x*x.x + x.y*x.y + x.z*x.z + x.w*x.w
                 + y.x*y.x + y.y*y.y + y.z*y.z + y.w*y.w;
        }
        c2v += __shfl_xor(c2v, 16, 64);   // reduce across quads
        c2v += __shfl_xor(c2v, 32, 64);
    }

    // ---- mask B-fragments: this wave owns col-tiles wave*2 and wave*2+1 ----
    v8s mhi0, mlo0, mhi1, mlo1;
    {
        V8U ph, pl;
        #pragma unroll
        for (int j = 0; j < 8; j++) {
            float mv = (quad < 2) ? cluster_mask[(quad * 8 + j) * FDIM + (wave * 2) * 16 + l16] : 0.f;
            ushort_t h = f2bf(mv);
            ph.u[j] = h; pl.u[j] = f2bf(mv - bf2f(h));
        }
        mhi0 = ph.v; mlo0 = pl.v;
        #pragma unroll
        for (int j = 0; j < 8; j++) {
            float mv = (quad < 2) ? cluster_mask[(quad * 8 + j) * FDIM + (wave * 2 + 1) * 16 + l16] : 0.f;
            ushort_t h = f2bf(mv);
            ph.u[j] = h; pl.u[j] = f2bf(mv - bf2f(h));
        }
        mhi1 = ph.v; mlo1 = pl.v;
    }

    // ---- neighbor gather pipeline ----
    int idx0 = neigh_idx[(size_t)b * S];
    float4 n4 = *(const float4*)(neigh_table + (size_t)idx0 * FDIM + f0);
    int idx_next = (S > 1) ? neigh_idx[(size_t)b * S + 1] : 0;

    float attsum = 0.f;
    // acc[ct][r]: rows (quad*4+r)&7, col (wave*2+ct)*16 + l16
    float accA0 = 0.f, accA1 = 0.f, accA2 = 0.f, accA3 = 0.f;
    float accB0 = 0.f, accB1 = 0.f, accB2 = 0.f, accB3 = 0.f;

    for (int s = 0; s < S; s++) {
        const int buf = s & 1;
        const float4 cur = n4;
        if (s + 1 < S) {
            n4 = *(const float4*)(neigh_table + (size_t)idx_next * FDIM + f0);
            if (s + 2 < S) idx_next = neigh_idx[(size_t)b * S + s + 2];
        }

        // stage f32 N
        *(float4*)(nf32[buf] + row * 132 + f0) = cur;
        // stage bf16 N, XOR-swizzled 16B slots (conflict-free A-frag reads)
        {
            ushort_t h0 = f2bf(cur.x), h1 = f2bf(cur.y), h2 = f2bf(cur.z), h3 = f2bf(cur.w);
            uint2 pk;
            pk.x = (unsigned)h0 | ((unsigned)h1 << 16);
            pk.y = (unsigned)h2 | ((unsigned)h3 << 16);
            const int slot = (fq >> 1) ^ row;
            *(uint2*)((char*)(nbf[buf]) + row * 256 + slot * 16 + (fq & 1) * 8) = pk;
        }
        // logit + n2 butterflies (within each row's 32 lanes)
        float pn = cur.x * aN.x + cur.y * aN.y + cur.z * aN.z + cur.w * aN.w;
        float p2 = cur.x * cur.x + cur.y * cur.y + cur.z * cur.z + cur.w * cur.w;
        #pragma unroll
        for (int off = 1; off <= 16; off <<= 1) {
            pn += __shfl_xor(pn, off, 64);
            p2 += __shfl_xor(p2, off, 64);
        }
        const float att = __expf(fmaxf(ls + pn, 0.f));
        attsum += att;
        if (fq == 0) { attL[buf][row] = att; n2L[buf][row] = p2; }

        // ---- barrier 1: LDS drains only; global prefetch stays in flight ----
        asm volatile("s_waitcnt lgkmcnt(0)" ::: "memory");
        __builtin_amdgcn_s_barrier();
        asm volatile("" ::: "memory");

        if (wave == 0) {
            // cross[r][k] = sum_f N[r][f]*center[k][f]; A rows mirror &7
            v4f xacc = {0.f, 0.f, 0.f, 0.f};
            #pragma unroll
            for (int kk = 0; kk < 4; kk++) {
                const int r = l16 & 7;
                const int sl = (kk * 4 + quad) ^ r;
                v8s af = *(const v8s*)((char*)(nbf[buf]) + r * 256 + sl * 16);
                xacc = __builtin_amdgcn_mfma_f32_16x16x32_bf16(af, cbf[kk], xacc, 0, 0, 0);
            }
            if (quad < 2) {   // D rows quad*4+r = 0..7 are the valid ones
                const float4 n2r = *(const float4*)(&n2L[buf][quad * 4]);
                #pragma unroll
                for (int r = 0; r < 4; r++) {
                    const float n2v = (r == 0) ? n2r.x : (r == 1) ? n2r.y : (r == 2) ? n2r.z : n2r.w;
                    const float d  = n2v - 2.f * xacc[r] + c2v;
                    const float qv = 1.f / (d + 1.f);
                    const ushort_t h = f2bf(qv);
                    qhi[(quad * 4 + r) * QSTRIDE + l16] = h;
                    qlo[(quad * 4 + r) * QSTRIDE + l16] = f2bf(qv - bf2f(h));
                }
            }
        }

        // ---- barrier 2: q ready (lgkm-only; vmem stays in flight) ----
        asm volatile("s_waitcnt lgkmcnt(0)" ::: "memory");
        __builtin_amdgcn_s_barrier();
        asm volatile("" ::: "memory");

        // m-tiles: m[r][(wave*2+ct)*16+l16] = sum_k q[r][k]*mask[k][f]
        // A rows mirror &7; quads 2,3 k-range has zero B rows
        v8s aqh = *(const v8s*)(qhi + (l16 & 7) * QSTRIDE + (quad & 1) * 8);
        v8s aql = *(const v8s*)(qlo + (l16 & 7) * QSTRIDE + (quad & 1) * 8);
        const float4 attr = *(const float4*)(&attL[buf][(quad & 1) * 4]);

        v4f macA = {0.f, 0.f, 0.f, 0.f};
        macA = __builtin_amdgcn_mfma_f32_16x16x32_bf16(aqh, mhi0, macA, 0, 0, 0);
        macA = __builtin_amdgcn_mfma_f32_16x16x32_bf16(aql, mhi0, macA, 0, 0, 0);
        macA = __builtin_amdgcn_mfma_f32_16x16x32_bf16(aqh, mlo0, macA, 0, 0, 0);
        {
            const float* nfp = nf32[buf] + (wave * 2) * 16 + l16;
            accA0 = fmaf(attr.x * macA[0], nfp[(((quad & 1) * 4) + 0) * 132], accA0);
            accA1 = fmaf(attr.y * macA[1], nfp[(((quad & 1) * 4) + 1) * 132], accA1);
            accA2 = fmaf(attr.z * macA[2], nfp[(((quad & 1) * 4) + 2) * 132], accA2);
            accA3 = fmaf(attr.w * macA[3], nfp[(((quad & 1) * 4) + 3) * 132], accA3);
        }
        v4f macB = {0.f, 0.f, 0.f, 0.f};
        macB = __builtin_amdgcn_mfma_f32_16x16x32_bf16(aqh, mhi1, macB, 0, 0, 0);
        macB = __builtin_amdgcn_mfma_f32_16x16x32_bf16(aql, mhi1, macB, 0, 0, 0);
        macB = __builtin_amdgcn_mfma_f32_16x16x32_bf16(aqh, mlo1, macB, 0, 0, 0);
        {
            const float* nfp = nf32[buf] + (wave * 2 + 1) * 16 + l16;
            accB0 = fmaf(attr.x * macB[0], nfp[(((quad & 1) * 4) + 0) * 132], accB0);
            accB1 = fmaf(attr.y * macB[1], nfp[(((quad & 1) * 4) + 1) * 132], accB1);
            accB2 = fmaf(attr.z * macB[2], nfp[(((quad & 1) * 4) + 2) * 132], accB2);
            accB3 = fmaf(attr.w * macB[3], nfp[(((quad & 1) * 4) + 3) * 132], accB3);
        }
    }

    // ---- normalize + write neigh-agg half of comb (rows 0..7 = quads 0,1) ----
    if (fq == 0) invL[row] = 1.f / attsum;
    __syncthreads();
    if (quad < 2) {
        const float4 invr = *(const float4*)(&invL[quad * 4]);
        ushort_t* cpA = comb + 128 + (wave * 2) * 16 + l16;
        cpA[(quad * 4 + 0) * CSTRIDE] = f2bf(accA0 * invr.x);
        cpA[(quad * 4 + 1) * CSTRIDE] = f2bf(accA1 * invr.y);
        cpA[(quad * 4 + 2) * CSTRIDE] = f2bf(accA2 * invr.z);
        cpA[(quad * 4 + 3) * CSTRIDE] = f2bf(accA3 * invr.w);
        ushort_t* cpB = comb + 128 + (wave * 2 + 1) * 16 + l16;
        cpB[(quad * 4 + 0) * CSTRIDE] = f2bf(accB0 * invr.x);
        cpB[(quad * 4 + 1) * CSTRIDE] = f2bf(accB1 * invr.y);
        cpB[(quad * 4 + 2) * CSTRIDE] = f2bf(accB2 * invr.z);
        cpB[(quad * 4 + 3) * CSTRIDE] = f2bf(accB3 * invr.w);
    }

    // ---------------- phase B: out[8][E] = relu(comb @ Wb^T) ----------------
    const int Ntiles = (E + 15) >> 4;

    // prefetch this wave's first W tile before the barrier (hides L2 latency)
    v8s bfr[8];
    {
        const int nt0 = (wave < Ntiles) ? wave : 0;
        const ushort_t* wrow = Wb + (size_t)(nt0 * 16 + l16) * 256 + quad * 8;
        #pragma unroll
        for (int kk = 0; kk < 8; kk++)
            bfr[kk] = *(const v8s*)(wrow + kk * 32);
    }

    __syncthreads();

    // A-fragments: A[m=l16&7][k = kk*32 + quad*8 + j] (rows 8..15 mirror)
    v8s afr[8];
    #pragma unroll
    for (int kk = 0; kk < 8; kk++)
        afr[kk] = *(const v8s*)(comb + (l16 & 7) * CSTRIDE + kk * 32 + quad * 8);

    for (int nt = wave; nt < Ntiles; nt += 4) {
        if (nt != wave) {
            const ushort_t* wrow = Wb + (size_t)(nt * 16 + l16) * 256 + quad * 8;
            #pragma unroll
            for (int kk = 0; kk < 8; kk++)
                bfr[kk] = *(const v8s*)(wrow + kk * 32);
        }
        v4f acc = {0.f, 0.f, 0.f, 0.f};
        #pragma unroll
        for (int kk = 0; kk < 8; kk++)
            acc = __builtin_amdgcn_mfma_f32_16x16x32_bf16(afr[kk], bfr[kk], acc, 0, 0, 0);
        const int gcol = nt * 16 + l16;
        if (gcol < E && quad < 2) {   // D rows quad*4+rr valid 0..7 only
            #pragma unroll
            for (int rr = 0; rr < 4; rr++) {
                const int grow = b0 + quad * 4 + rr;
                if (grow < B)
                    out[(size_t)grow * E + gcol] = fmaxf(acc[rr], 0.f);
            }
        }
    }
}

extern "C" void kernel_launch(void* const* d_in, const int* in_sizes, int n_in,
                              void* d_out, int out_size, void* d_ws, size_t ws_size,
                              hipStream_t stream) {
    const int*   nodes        = (const int*)d_in[0];
    const int*   neigh_idx    = (const int*)d_in[1];
    const float* self_table   = (const float*)d_in[2];
    const float* neigh_table  = (const float*)d_in[3];
    const float* center       = (const float*)d_in[4];
    const float* cluster_mask = (const float*)d_in[5];
    const float* weight       = (const float*)d_in[6];
    const float* alpha        = (const float*)d_in[7];
    float* out = (float*)d_out;

    int B = in_sizes[0];
    int S = in_sizes[1] / B;
    int E = in_sizes[6] / (2 * FDIM);

    int Np = ((E + 15) / 16) * 16;
    ushort_t* Wb = (ushort_t*)d_ws;   // Np x 256 bf16

    long totalW = (long)Np * 256;
    long validW = (long)E * 256;
    int blksW = (int)((totalW + 1023) / 1024);
    pack_weight<<<blksW, 256, 0, stream>>>(weight, Wb, totalW, validW);

    int nblk = (B + 7) / 8;
    fused_agg<<<nblk, 256, 0, stream>>>(
        nodes, neigh_idx, self_table, neigh_table, center, cluster_mask, alpha,
        Wb, out, B, S, E);
}

// Round 7
// 242.017 us; speedup vs baseline: 1.2464x; 1.2464x over previous
//
#include <hip/hip_runtime.h>
#include <hip/hip_bf16.h>

typedef unsigned short ushort_t;
typedef __attribute__((ext_vector_type(4))) float v4f;
typedef __attribute__((ext_vector_type(8))) short v8s;

#define FDIM 128
#define KCLUST 16
#define CSTRIDE 264   // combined-row stride in bf16 elems (264*2B = 528B)
#define QSTRIDE 24    // q row stride in shorts (48B)

__device__ __forceinline__ ushort_t f2bf(float x) {
    unsigned int u = __float_as_uint(x);
    unsigned int r = (u + 0x7fffu + ((u >> 16) & 1u)) >> 16;
    return (ushort_t)r;
}
__device__ __forceinline__ float bf2f(ushort_t h) {
    return __uint_as_float((unsigned int)h << 16);
}

union V8U { v8s v; ushort_t u[8]; };

// ---------------------------------------------------------------------------
// Kernel 1: cast weight (E x 256 f32) -> bf16, padded to Np rows (zeros).
// ---------------------------------------------------------------------------
__global__ void pack_weight(const float* __restrict__ W, ushort_t* __restrict__ Wb,
                            long total, long valid) {
    long i = ((long)blockIdx.x * blockDim.x + threadIdx.x) * 4;
    if (i >= total) return;
    float4 v;
    if (i < valid) v = *(const float4*)(W + i);
    else           v = make_float4(0.f, 0.f, 0.f, 0.f);
    ushort_t* dst = Wb + i;
    dst[0] = f2bf(v.x); dst[1] = f2bf(v.y); dst[2] = f2bf(v.z); dst[3] = f2bf(v.w);
}

// ---------------------------------------------------------------------------
// Kernel 2 (fused), v8: v7 with the register cap fixed.
//   Empirical law from v2/v3/v7: __launch_bounds__ 2nd arg caps VGPR at
//   ~256/arg regardless of block size. v7's (256,6) -> cap 40 -> ~90-reg
//   live set spilled (WRITE_SIZE 93MB, dur 2x). v8 uses (256,2) -> cap 128:
//   no spill, VGPR<=128 still allows 4 waves/SIMD = 4 resident blocks/CU,
//   which is the cross-block overlap the small-block design needs.
//   Everything else identical to v7 (8 rows / 256 thr / 4 waves / ~18KB LDS).
// ---------------------------------------------------------------------------
__global__ __launch_bounds__(256, 2) void fused_agg(
    const int* __restrict__ nodes, const int* __restrict__ neigh_idx,
    const float* __restrict__ self_table, const float* __restrict__ neigh_table,
    const float* __restrict__ center, const float* __restrict__ cluster_mask,
    const float* __restrict__ alpha, const ushort_t* __restrict__ Wb,
    float* __restrict__ out, int B, int S, int E) {

    __shared__ __align__(16) ushort_t comb[8 * CSTRIDE];      // 4224 B
    __shared__ __align__(16) ushort_t nbf[2][8 * 128];        // 4096 B (swizzled bf16 N)
    __shared__ __align__(16) float    nf32[2][8 * 132];       // 8448 B (f32 N, pad 132)
    __shared__ __align__(16) float    attL[2][8];
    __shared__ __align__(16) float    n2L[2][8];
    __shared__ __align__(16) ushort_t qhi[8 * QSTRIDE];       // 384 B
    __shared__ __align__(16) ushort_t qlo[8 * QSTRIDE];       // 384 B
    __shared__ __align__(16) float    invL[8];

    const int t    = threadIdx.x;
    const int lane = t & 63, wave = t >> 6;   // 4 waves
    const int row  = t >> 5;                  // 0..7 (2 rows per wave)
    const int fq   = t & 31;                  // feat-quad within row
    const int f0   = fq << 2;                 // first of this thread's 4 feats
    const int l16  = lane & 15, quad = lane >> 4;

    const int b0 = blockIdx.x * 8;
    int b = b0 + row; if (b >= B) b = B - 1;  // clamp loads; stores guarded

    const float4 aS = *(const float4*)(alpha + f0);
    const float4 aN = *(const float4*)(alpha + FDIM + f0);

    // ---- self features: stage to comb (bf16) + logit_self butterfly ----
    float ls;
    {
        size_t node = (size_t)nodes[b];
        float4 sf = *(const float4*)(self_table + node * FDIM + f0);
        ushort_t h0 = f2bf(sf.x), h1 = f2bf(sf.y), h2 = f2bf(sf.z), h3 = f2bf(sf.w);
        uint2 pk;
        pk.x = (unsigned)h0 | ((unsigned)h1 << 16);
        pk.y = (unsigned)h2 | ((unsigned)h3 << 16);
        *(uint2*)(comb + row * CSTRIDE + f0) = pk;
        ls = sf.x * aS.x + sf.y * aS.y + sf.z * aS.z + sf.w * aS.w;
        #pragma unroll
        for (int off = 1; off <= 16; off <<= 1) ls += __shfl_xor(ls, off, 64);
    }

    // ---- wave 0: center B-fragments (bf16) + c2 (exact f32) ----
    v8s cbf[4]; float c2v = 0.f;
    if (wave == 0) {
        const float* crow = center + l16 * FDIM;
        #pragma unroll
        for (int kk = 0; kk < 4; kk++) {
            const float* p = crow + kk * 32 + quad * 8;
            float4 x = *(const float4*)p;
            float4 y = *(const float4*)(p + 4);
            V8U pk;
            pk.u[0] = f2bf(x.x); pk.u[1] = f2bf(x.y); pk.u[2] = f2bf(x.z); pk.u[3] = f2bf(x.w);
            pk.u[4] = f2bf(y.x); pk.u[5] = f2bf(y.y); pk.u[6] = f2bf(y.z); pk.u[7] = f2bf(y.w);
            cbf[kk] = pk.v;
            c2v += x.x*x.x + x.y*x.y + x.z*x.z + x.w*x.w
                 + y.x*y.x + y.y*y.y + y.z*y.z + y.w*y.w;
        }
        c2v += __shfl_xor(c2v, 16, 64);   // reduce across quads
        c2v += __shfl_xor(c2v, 32, 64);
    }

    // ---- mask B-fragments: this wave owns col-tiles wave*2 and wave*2+1 ----
    v8s mhi0, mlo0, mhi1, mlo1;
    {
        V8U ph, pl;
        #pragma unroll
        for (int j = 0; j < 8; j++) {
            float mv = (quad < 2) ? cluster_mask[(quad * 8 + j) * FDIM + (wave * 2) * 16 + l16] : 0.f;
            ushort_t h = f2bf(mv);
            ph.u[j] = h; pl.u[j] = f2bf(mv - bf2f(h));
        }
        mhi0 = ph.v; mlo0 = pl.v;
        #pragma unroll
        for (int j = 0; j < 8; j++) {
            float mv = (quad < 2) ? cluster_mask[(quad * 8 + j) * FDIM + (wave * 2 + 1) * 16 + l16] : 0.f;
            ushort_t h = f2bf(mv);
            ph.u[j] = h; pl.u[j] = f2bf(mv - bf2f(h));
        }
        mhi1 = ph.v; mlo1 = pl.v;
    }

    // ---- neighbor gather pipeline ----
    int idx0 = neigh_idx[(size_t)b * S];
    float4 n4 = *(const float4*)(neigh_table + (size_t)idx0 * FDIM + f0);
    int idx_next = (S > 1) ? neigh_idx[(size_t)b * S + 1] : 0;

    float attsum = 0.f;
    // acc[ct][r]: rows (quad*4+r)&7, col (wave*2+ct)*16 + l16
    float accA0 = 0.f, accA1 = 0.f, accA2 = 0.f, accA3 = 0.f;
    float accB0 = 0.f, accB1 = 0.f, accB2 = 0.f, accB3 = 0.f;

    for (int s = 0; s < S; s++) {
        const int buf = s & 1;
        const float4 cur = n4;
        if (s + 1 < S) {
            n4 = *(const float4*)(neigh_table + (size_t)idx_next * FDIM + f0);
            if (s + 2 < S) idx_next = neigh_idx[(size_t)b * S + s + 2];
        }

        // stage f32 N
        *(float4*)(nf32[buf] + row * 132 + f0) = cur;
        // stage bf16 N, XOR-swizzled 16B slots (conflict-free A-frag reads)
        {
            ushort_t h0 = f2bf(cur.x), h1 = f2bf(cur.y), h2 = f2bf(cur.z), h3 = f2bf(cur.w);
            uint2 pk;
            pk.x = (unsigned)h0 | ((unsigned)h1 << 16);
            pk.y = (unsigned)h2 | ((unsigned)h3 << 16);
            const int slot = (fq >> 1) ^ row;
            *(uint2*)((char*)(nbf[buf]) + row * 256 + slot * 16 + (fq & 1) * 8) = pk;
        }
        // logit + n2 butterflies (within each row's 32 lanes)
        float pn = cur.x * aN.x + cur.y * aN.y + cur.z * aN.z + cur.w * aN.w;
        float p2 = cur.x * cur.x + cur.y * cur.y + cur.z * cur.z + cur.w * cur.w;
        #pragma unroll
        for (int off = 1; off <= 16; off <<= 1) {
            pn += __shfl_xor(pn, off, 64);
            p2 += __shfl_xor(p2, off, 64);
        }
        const float att = __expf(fmaxf(ls + pn, 0.f));
        attsum += att;
        if (fq == 0) { attL[buf][row] = att; n2L[buf][row] = p2; }

        // ---- barrier 1: LDS drains only; global prefetch stays in flight ----
        asm volatile("s_waitcnt lgkmcnt(0)" ::: "memory");
        __builtin_amdgcn_s_barrier();
        asm volatile("" ::: "memory");

        if (wave == 0) {
            // cross[r][k] = sum_f N[r][f]*center[k][f]; A rows mirror &7
            v4f xacc = {0.f, 0.f, 0.f, 0.f};
            #pragma unroll
            for (int kk = 0; kk < 4; kk++) {
                const int r = l16 & 7;
                const int sl = (kk * 4 + quad) ^ r;
                v8s af = *(const v8s*)((char*)(nbf[buf]) + r * 256 + sl * 16);
                xacc = __builtin_amdgcn_mfma_f32_16x16x32_bf16(af, cbf[kk], xacc, 0, 0, 0);
            }
            if (quad < 2) {   // D rows quad*4+r = 0..7 are the valid ones
                const float4 n2r = *(const float4*)(&n2L[buf][quad * 4]);
                #pragma unroll
                for (int r = 0; r < 4; r++) {
                    const float n2v = (r == 0) ? n2r.x : (r == 1) ? n2r.y : (r == 2) ? n2r.z : n2r.w;
                    const float d  = n2v - 2.f * xacc[r] + c2v;
                    const float qv = 1.f / (d + 1.f);
                    const ushort_t h = f2bf(qv);
                    qhi[(quad * 4 + r) * QSTRIDE + l16] = h;
                    qlo[(quad * 4 + r) * QSTRIDE + l16] = f2bf(qv - bf2f(h));
                }
            }
        }

        // ---- barrier 2: q ready (lgkm-only; vmem stays in flight) ----
        asm volatile("s_waitcnt lgkmcnt(0)" ::: "memory");
        __builtin_amdgcn_s_barrier();
        asm volatile("" ::: "memory");

        // m-tiles: m[r][(wave*2+ct)*16+l16] = sum_k q[r][k]*mask[k][f]
        // A rows mirror &7; quads 2,3 k-range has zero B rows
        v8s aqh = *(const v8s*)(qhi + (l16 & 7) * QSTRIDE + (quad & 1) * 8);
        v8s aql = *(const v8s*)(qlo + (l16 & 7) * QSTRIDE + (quad & 1) * 8);
        const float4 attr = *(const float4*)(&attL[buf][(quad & 1) * 4]);

        v4f macA = {0.f, 0.f, 0.f, 0.f};
        macA = __builtin_amdgcn_mfma_f32_16x16x32_bf16(aqh, mhi0, macA, 0, 0, 0);
        macA = __builtin_amdgcn_mfma_f32_16x16x32_bf16(aql, mhi0, macA, 0, 0, 0);
        macA = __builtin_amdgcn_mfma_f32_16x16x32_bf16(aqh, mlo0, macA, 0, 0, 0);
        {
            const float* nfp = nf32[buf] + (wave * 2) * 16 + l16;
            accA0 = fmaf(attr.x * macA[0], nfp[(((quad & 1) * 4) + 0) * 132], accA0);
            accA1 = fmaf(attr.y * macA[1], nfp[(((quad & 1) * 4) + 1) * 132], accA1);
            accA2 = fmaf(attr.z * macA[2], nfp[(((quad & 1) * 4) + 2) * 132], accA2);
            accA3 = fmaf(attr.w * macA[3], nfp[(((quad & 1) * 4) + 3) * 132], accA3);
        }
        v4f macB = {0.f, 0.f, 0.f, 0.f};
        macB = __builtin_amdgcn_mfma_f32_16x16x32_bf16(aqh, mhi1, macB, 0, 0, 0);
        macB = __builtin_amdgcn_mfma_f32_16x16x32_bf16(aql, mhi1, macB, 0, 0, 0);
        macB = __builtin_amdgcn_mfma_f32_16x16x32_bf16(aqh, mlo1, macB, 0, 0, 0);
        {
            const float* nfp = nf32[buf] + (wave * 2 + 1) * 16 + l16;
            accB0 = fmaf(attr.x * macB[0], nfp[(((quad & 1) * 4) + 0) * 132], accB0);
            accB1 = fmaf(attr.y * macB[1], nfp[(((quad & 1) * 4) + 1) * 132], accB1);
            accB2 = fmaf(attr.z * macB[2], nfp[(((quad & 1) * 4) + 2) * 132], accB2);
            accB3 = fmaf(attr.w * macB[3], nfp[(((quad & 1) * 4) + 3) * 132], accB3);
        }
    }

    // ---- normalize + write neigh-agg half of comb (rows 0..7 = quads 0,1) ----
    if (fq == 0) invL[row] = 1.f / attsum;
    __syncthreads();
    if (quad < 2) {
        const float4 invr = *(const float4*)(&invL[quad * 4]);
        ushort_t* cpA = comb + 128 + (wave * 2) * 16 + l16;
        cpA[(quad * 4 + 0) * CSTRIDE] = f2bf(accA0 * invr.x);
        cpA[(quad * 4 + 1) * CSTRIDE] = f2bf(accA1 * invr.y);
        cpA[(quad * 4 + 2) * CSTRIDE] = f2bf(accA2 * invr.z);
        cpA[(quad * 4 + 3) * CSTRIDE] = f2bf(accA3 * invr.w);
        ushort_t* cpB = comb + 128 + (wave * 2 + 1) * 16 + l16;
        cpB[(quad * 4 + 0) * CSTRIDE] = f2bf(accB0 * invr.x);
        cpB[(quad * 4 + 1) * CSTRIDE] = f2bf(accB1 * invr.y);
        cpB[(quad * 4 + 2) * CSTRIDE] = f2bf(accB2 * invr.z);
        cpB[(quad * 4 + 3) * CSTRIDE] = f2bf(accB3 * invr.w);
    }

    // ---------------- phase B: out[8][E] = relu(comb @ Wb^T) ----------------
    const int Ntiles = (E + 15) >> 4;

    // prefetch this wave's first W tile before the barrier (hides L2 latency)
    v8s bfr[8];
    {
        const int nt0 = (wave < Ntiles) ? wave : 0;
        const ushort_t* wrow = Wb + (size_t)(nt0 * 16 + l16) * 256 + quad * 8;
        #pragma unroll
        for (int kk = 0; kk < 8; kk++)
            bfr[kk] = *(const v8s*)(wrow + kk * 32);
    }

    __syncthreads();

    // A-fragments: A[m=l16&7][k = kk*32 + quad*8 + j] (rows 8..15 mirror)
    v8s afr[8];
    #pragma unroll
    for (int kk = 0; kk < 8; kk++)
        afr[kk] = *(const v8s*)(comb + (l16 & 7) * CSTRIDE + kk * 32 + quad * 8);

    for (int nt = wave; nt < Ntiles; nt += 4) {
        if (nt != wave) {
            const ushort_t* wrow = Wb + (size_t)(nt * 16 + l16) * 256 + quad * 8;
            #pragma unroll
            for (int kk = 0; kk < 8; kk++)
                bfr[kk] = *(const v8s*)(wrow + kk * 32);
        }
        v4f acc = {0.f, 0.f, 0.f, 0.f};
        #pragma unroll
        for (int kk = 0; kk < 8; kk++)
            acc = __builtin_amdgcn_mfma_f32_16x16x32_bf16(afr[kk], bfr[kk], acc, 0, 0, 0);
        const int gcol = nt * 16 + l16;
        if (gcol < E && quad < 2) {   // D rows quad*4+rr valid 0..7 only
            #pragma unroll
            for (int rr = 0; rr < 4; rr++) {
                const int grow = b0 + quad * 4 + rr;
                if (grow < B)
                    out[(size_t)grow * E + gcol] = fmaxf(acc[rr], 0.f);
            }
        }
    }
}

extern "C" void kernel_launch(void* const* d_in, const int* in_sizes, int n_in,
                              void* d_out, int out_size, void* d_ws, size_t ws_size,
                              hipStream_t stream) {
    const int*   nodes        = (const int*)d_in[0];
    const int*   neigh_idx    = (const int*)d_in[1];
    const float* self_table   = (const float*)d_in[2];
    const float* neigh_table  = (const float*)d_in[3];
    const float* center       = (const float*)d_in[4];
    const float* cluster_mask = (const float*)d_in[5];
    const float* weight       = (const float*)d_in[6];
    const float* alpha        = (const float*)d_in[7];
    float* out = (float*)d_out;

    int B = in_sizes[0];
    int S = in_sizes[1] / B;
    int E = in_sizes[6] / (2 * FDIM);

    int Np = ((E + 15) / 16) * 16;
    ushort_t* Wb = (ushort_t*)d_ws;   // Np x 256 bf16

    long totalW = (long)Np * 256;
    long validW = (long)E * 256;
    int blksW = (int)((totalW + 1023) / 1024);
    pack_weight<<<blksW, 256, 0, stream>>>(weight, Wb, totalW, validW);

    int nblk = (B + 7) / 8;
    fused_agg<<<nblk, 256, 0, stream>>>(
        nodes, neigh_idx, self_table, neigh_table, center, cluster_mask, alpha,
        Wb, out, B, S, E);
}